// Round 1
// baseline (1107.307 us; speedup 1.0000x reference)
//
#include <hip/hip_runtime.h>
#include <stdint.h>

constexpr int D_MODEL = 4096;
constexpr int RANK    = 32;
constexpr int TPB     = 8;     // tokens per block (halved: fits regs + full gather in flight)
constexpr int THREADS = 128;   // 2 waves
constexpr int PASSES  = D_MODEL / (THREADS * 4);   // 8 passes of 512 floats
constexpr float SCALING = 0.5f;  // ALPHA / RANK = 16/32

typedef float f32x4 __attribute__((ext_vector_type(4)));

__global__ __launch_bounds__(THREADS, 4)
void lora_embed_kernel(const int* __restrict__ ids,
                       const int* __restrict__ wq,     // int8 promoted to int32 by harness
                       const float* __restrict__ scale,
                       const float* __restrict__ A,
                       const float* __restrict__ Bm,
                       float* __restrict__ out)
{
    // A staged [r][t]: the 8 per-token a-values for a given r are contiguous
    // -> 2x ds_read_b128 broadcast reads per r.
    __shared__ float sA[RANK][TPB];
    __shared__ int   sTok[TPB];

    const int tid = threadIdx.x;
    const int t0  = blockIdx.x * TPB;

    if (tid < TPB) sTok[tid] = ids[t0 + tid];
    __syncthreads();

    // Stage 8 adapter_A rows (SCALING folded): 256 floats, 2 per thread.
    {
        int i = tid;                       // t = i>>5 in 0..3, r = i&31
        int t = i >> 5, r = i & 31;
        sA[r][t] = A[(int64_t)sTok[t] * RANK + r] * SCALING;
        i += THREADS; t = i >> 5; r = i & 31;
        sA[r][t] = A[(int64_t)sTok[t] * RANK + r] * SCALING;
    }
    __syncthreads();

    const float s = scale[0];

    int wrow[TPB];                         // tok*4096 < 2^31: keep 32-bit
    #pragma unroll
    for (int t = 0; t < TPB; ++t) wrow[t] = sTok[t] * D_MODEL;

    const f32x4* sA4 = (const f32x4*)&sA[0][0];   // [RANK][2]

    for (int p = 0; p < PASSES; ++p) {
        const int d = p * (THREADS * 4) + (tid << 2);

        // Issue ALL base-row gathers FIRST: ~900-cyc HBM latency hides under
        // the 32x8x4-FMA rank loop below. w[8] = 32 VGPRs, fits with acc[8].
        int4 w[TPB];
        #pragma unroll
        for (int t = 0; t < TPB; ++t)
            w[t] = *(const int4*)(wq + wrow[t] + d);

        f32x4 acc[TPB];
        const f32x4 zero = {0.f, 0.f, 0.f, 0.f};
        #pragma unroll
        for (int t = 0; t < TPB; ++t) acc[t] = zero;

        // B float4 loaded once per r (L2-resident), reused across 8 tokens.
        const float* bp = Bm + d;
        #pragma unroll 4
        for (int r = 0; r < RANK; ++r) {
            const f32x4 b   = *(const f32x4*)(bp + r * D_MODEL);
            const f32x4 alo = sA4[r * 2 + 0];
            const f32x4 ahi = sA4[r * 2 + 1];
            acc[0] += alo.x * b;
            acc[1] += alo.y * b;
            acc[2] += alo.z * b;
            acc[3] += alo.w * b;
            acc[4] += ahi.x * b;
            acc[5] += ahi.y * b;
            acc[6] += ahi.z * b;
            acc[7] += ahi.w * b;
        }

        // Dequant + add; nontemporal store (pure streaming output, spare L2 for B/wq).
        #pragma unroll
        for (int t = 0; t < TPB; ++t) {
            f32x4 o;
            o.x = (float)w[t].x * s + acc[t].x;
            o.y = (float)w[t].y * s + acc[t].y;
            o.z = (float)w[t].z * s + acc[t].z;
            o.w = (float)w[t].w * s + acc[t].w;
            __builtin_nontemporal_store(o, (f32x4*)(out + (int64_t)(t0 + t) * D_MODEL + d));
        }
    }
}

extern "C" void kernel_launch(void* const* d_in, const int* in_sizes, int n_in,
                              void* d_out, int out_size, void* d_ws, size_t ws_size,
                              hipStream_t stream)
{
    const int*   ids   = (const int*)d_in[0];
    const int*   wq    = (const int*)d_in[1];   // int8 promoted to int32 by harness
    const float* scale = (const float*)d_in[2];
    const float* A     = (const float*)d_in[3];
    const float* Bm    = (const float*)d_in[4];
    float* out = (float*)d_out;

    const int n_tok  = in_sizes[0];      // 4*4096 = 16384
    const int blocks = n_tok / TPB;      // 2048
    lora_embed_kernel<<<blocks, THREADS, 0, stream>>>(ids, wq, scale, A, Bm, out);
}